// Round 4
// baseline (217.817 us; speedup 1.0000x reference)
//
#include <hip/hip_runtime.h>
#include <hip/hip_bf16.h>

#define T_  30
#define B_  64
#define V_  32
#define F_  128
#define L_  64
#define LF_ 64
#define TH_ 20
#define H_  4
#define HD_ 32

typedef __attribute__((ext_vector_type(8))) short bf16x8;   // 8 bf16 = 4 VGPR
typedef __attribute__((ext_vector_type(4))) short bf16x4;   // 4 bf16 = 2 VGPR
typedef __attribute__((ext_vector_type(4))) float f32x4;
#define MFMA(a,b,c) __builtin_amdgcn_mfma_f32_16x16x32_bf16(a, b, c, 0, 0, 0)

// K=16 bf16 MFMA (v_mfma_f32_16x16x16_bf16). Builtin spelling is the CDNA2
// "1k" form; guard with __HIP_DEVICE_COMPILE__ so the x86 host pass (which
// can't see aux-target builtins via __has_builtin) never parses it.
__device__ __forceinline__ f32x4 mfma16(bf16x4 a, bf16x4 b, f32x4 c) {
#if defined(__HIP_DEVICE_COMPILE__)
    return __builtin_amdgcn_mfma_f32_16x16x16bf16_1k(a, b, c, 0, 0, 0);
#else
    (void)a; (void)b; return c;
#endif
}

__device__ __forceinline__ float bf1(unsigned short u) {
    unsigned int x = ((unsigned int)u) << 16; float f; __builtin_memcpy(&f, &x, 4); return f;
}
// pack two f32 -> two bf16 (RTNE, v_cvt_pk_bf16_f32); lo half = a, hi half = b
__device__ __forceinline__ unsigned int cvtpk(float a, float b) {
    __hip_bfloat162 h = __float22bfloat162_rn(make_float2(a, b));
    unsigned int r; __builtin_memcpy(&r, &h, 4); return r;
}
__device__ __forceinline__ void st4pk(unsigned short* p, float a, float b, float c, float d) {
    uint2 u = { cvtpk(a, b), cvtpk(c, d) };
    *(uint2*)p = u;
}
// XOR-16B swizzle keyed on row&7 (T2): ushort-index helpers.
__device__ __forceinline__ int swz128(int r, int c) { return r * 128 + (c ^ ((r & 7) << 3)); }
__device__ __forceinline__ int swz64 (int r, int c) { return r * 64  + (c ^ ((r & 7) << 3)); }
// Load one MFMA A/B-fragment (8 bf16) from a weight matrix of either dtype.
__device__ __forceinline__ bf16x8 ldWfrag(const void* W, int off, bool isBf16) {
    if (isBf16) return *(const bf16x8*)((const unsigned short*)W + off);
    const float* p = (const float*)W + off;
    float4 a = *(const float4*)p;
    float4 b = *(const float4*)(p + 4);
    uint4 u = { cvtpk(a.x, a.y), cvtpk(a.z, a.w), cvtpk(b.x, b.y), cvtpk(b.z, b.w) };
    bf16x8 r; __builtin_memcpy(&r, &u, 16); return r;
}

// One block per (b,v). 8 waves: wave w -> head h=w>>1, half s=w&1.
// LDS cut to exactly 40960 B -> 4 blocks/CU x 8 waves = 32 waves/CU (HW cap).
// Key trick: mfma fragment identity — the projection C-layouts ARE the
// consumer's K=16 A/B fragments on the same lane:
//   V (unswapped B-pass) C[l][f] -> PV A-fragments, kept in 8 VGPRs (sVt gone);
//   P (scores C[l][t]) -> PV B-fragment for the wave's own t-half; only the
//   partner t-half goes through LDS (sPx, overlaying dead staging buffers).
// Softmax normalization folded into P (rowsum via 2 shfl_xor) -> O unscaled.
// 4 barriers. All LDS XOR-swizzled (no pads).
__global__ __launch_bounds__(512, 8)
void lane_attn_kernel(const void* __restrict__ veh,    // [T,B,V,F]
                      const void* __restrict__ lanes,  // [B,V,L,LF]
                      const void* __restrict__ maskp,  // [TH,B,V,L] uint8 or int32 (probed)
                      const void* __restrict__ Wk, const void* __restrict__ Wv,
                      const void* __restrict__ Wq, const void* __restrict__ Wc,
                      float* __restrict__ outp)        // [T,B,V,F] fp32
{
    const int bv    = blockIdx.x;
    const int tid   = threadIdx.x;
    const int w     = tid >> 6;
    const int h     = w >> 1;      // head
    const int shalf = w & 1;       // half within head
    const int lane  = tid & 63;
    const int quad  = lane >> 4;
    const int lm    = lane & 15;
    const int fbase = h * 32;
    const int fs    = fbase + shalf * 16;   // wave's 16-col f-slice

    // LDS (ushort units), 20480 ushorts = 40960 B total:
    //   sK    [64 l][128 f]   8192 u  (written B, read scores, dead after bar2.5)
    //   sReg1 8192 u: sLanes [64][64] + sVehB [32][128]  (A..C)
    //                 -> after bar2: sPx [8 slots][16 t][64 l]
    //   sReg2 4096 u: sQ [32][128]   (C..scores)
    //                 -> after bar2.5: sO [32][128]
    __shared__ __align__(16) unsigned short sK   [8192];
    __shared__ __align__(16) unsigned short sReg1[8192];
    __shared__ __align__(16) unsigned short sReg2[4096];
    unsigned short* sLanes = sReg1;
    unsigned short* sVehB  = sReg1 + 4096;
    unsigned short* sPx    = sReg1;
    unsigned short* sQ     = sReg2;
    unsigned short* sO     = sReg2;

    // ---------- per-wave probes (wave-uniform, L2-hot after first blocks) ----------
    const unsigned short* vh16 = (const unsigned short*)veh;
    const int field = (vh16[2 * lane] >> 7) & 0xFF;
    const bool isBf16 = __popcll(__ballot(field >= 100 && field <= 130)) >= 32;
    const unsigned char* mbp = (const unsigned char*)maskp;
    const bool maskByte = (__ballot(mbp[4 * lane + 1] != 0) != 0ULL);

    // ---------- per-lane mask OR over TH (l = lane) -> wave-uniform bitmask ----------
    bool ok;
    {
        const int* mi = (const int*)maskp;
        int o = 0;
        #pragma unroll
        for (int th = 0; th < TH_; ++th) {
            const size_t e = (size_t)th * (B_ * V_ * L_) + (size_t)bv * L_ + lane;
            o |= maskByte ? (int)mbp[e] : mi[e];
        }
        ok = (o != 0);
    }
    const unsigned long long mok = __ballot(ok);   // bit l = mask for lane-row l

    // ---------- weight fragments used before bar2 (issue early, hide HBM) ----------
    bf16x8 wbK[2], wbV[2], wq[4];
    #pragma unroll
    for (int kt = 0; kt < 2; ++kt) {
        const int off = (fs + lm) * 64 + kt * 32 + quad * 8;
        wbK[kt] = ldWfrag(Wk, off, isBf16);
        wbV[kt] = ldWfrag(Wv, off, isBf16);
    }
    #pragma unroll
    for (int kt = 0; kt < 4; ++kt)
        wq[kt] = ldWfrag(Wq, (fs + lm) * 128 + kt * 32 + quad * 8, isBf16);

    // ---------- Phase A: stage lanes[64][64] + veh[32][128] as bf16 (swizzled) ----------
    if (isBf16) {
        {   // lanes: 512 x 16B chunks, one per thread
            const int l = tid >> 3, g = tid & 7;
            uint4 x = *(const uint4*)((const unsigned short*)lanes + (size_t)bv * 4096 + tid * 8);
            *(uint4*)&sLanes[swz64(l, g * 8)] = x;
        }
        {   // veh: 32 rows x 16 granules = 512
            const int t = tid >> 4, g = tid & 15;
            uint4 x = {0, 0, 0, 0};
            if (t < T_)
                x = *(const uint4*)((const unsigned short*)veh + ((size_t)t * (B_ * V_) + bv) * F_ + g * 8);
            *(uint4*)&sVehB[swz128(t, g * 8)] = x;
        }
    } else {
        const float4* lf4 = (const float4*)lanes;
        #pragma unroll
        for (int rr = 0; rr < 2; ++rr) {
            const int u = tid + rr * 512;
            const int l = u >> 4, c = (u & 15) * 4;
            float4 x = lf4[bv * 1024 + u];
            uint2 y = { cvtpk(x.x, x.y), cvtpk(x.z, x.w) };
            *(uint2*)&sLanes[swz64(l, c)] = y;
        }
        #pragma unroll
        for (int rr = 0; rr < 2; ++rr) {
            const int u = tid + rr * 512;
            const int t = u >> 5, c = (u & 31) * 4;
            uint2 y = {0, 0};
            if (t < T_) {
                float4 x = ((const float4*)veh)[((size_t)t * (B_ * V_) + bv) * 32 + (u & 31)];
                y.x = cvtpk(x.x, x.y); y.y = cvtpk(x.z, x.w);
            }
            *(uint2*)&sVehB[swz128(t, c)] = y;
        }
    }
    __syncthreads();   // barrier 1: staging visible

    // ---------- Phase B-K: K projection (swapped: A=Wk) -> sK[l][f] packed ----------
    {
        f32x4 accK[4];
        #pragma unroll
        for (int mt = 0; mt < 4; ++mt) accK[mt] = (f32x4)0.f;
        #pragma unroll
        for (int kt = 0; kt < 2; ++kt) {
            bf16x8 a[4];
            #pragma unroll
            for (int mt = 0; mt < 4; ++mt)
                a[mt] = *(const bf16x8*)&sLanes[swz64(mt * 16 + lm, kt * 32 + quad * 8)];
            #pragma unroll
            for (int mt = 0; mt < 4; ++mt) accK[mt] = MFMA(wbK[kt], a[mt], accK[mt]);  // C[f][l]
        }
        #pragma unroll
        for (int mt = 0; mt < 4; ++mt)
            st4pk(&sK[swz128(mt * 16 + lm, fs + quad * 4)],
                  accK[mt][0], accK[mt][1], accK[mt][2], accK[mt][3]);
    }

    // ---------- Phase B-V: V projection (unswapped) -> registers as PV A-frags ----------
    bf16x4 vb[4];   // vb[kt]: V[l=kt*16+quad*4+r][f=fs+lm]
    {
        f32x4 accV[4];
        #pragma unroll
        for (int mt = 0; mt < 4; ++mt) accV[mt] = (f32x4)0.f;
        #pragma unroll
        for (int kt = 0; kt < 2; ++kt) {
            bf16x8 a[4];
            #pragma unroll
            for (int mt = 0; mt < 4; ++mt)
                a[mt] = *(const bf16x8*)&sLanes[swz64(mt * 16 + lm, kt * 32 + quad * 8)];
            #pragma unroll
            for (int mt = 0; mt < 4; ++mt) accV[mt] = MFMA(a[mt], wbV[kt], accV[mt]);  // C[l][f]
        }
        #pragma unroll
        for (int mt = 0; mt < 4; ++mt) {
            uint2 y = { cvtpk(accV[mt][0], accV[mt][1]), cvtpk(accV[mt][2], accV[mt][3]) };
            __builtin_memcpy(&vb[mt], &y, 8);
        }
    }

    // ---------- Phase C: Q projection (swapped: A=Wq) -> sQ[t][g] packed, pre-scaled ----------
    {
        f32x4 acc[2];
        acc[0] = (f32x4)0.f; acc[1] = (f32x4)0.f;
        #pragma unroll
        for (int kt = 0; kt < 4; ++kt) {
            bf16x8 b[2];
            #pragma unroll
            for (int nt = 0; nt < 2; ++nt)
                b[nt] = *(const bf16x8*)&sVehB[swz128(nt * 16 + lm, kt * 32 + quad * 8)];
            #pragma unroll
            for (int nt = 0; nt < 2; ++nt) acc[nt] = MFMA(wq[kt], b[nt], acc[nt]);     // C[g][t]
        }
        const float sc = 0.17677669529663687f;   // 1/sqrt(32)
        #pragma unroll
        for (int nt = 0; nt < 2; ++nt)
            st4pk(&sQ[swz128(nt * 16 + lm, fs + quad * 4)],
                  acc[nt][0] * sc, acc[nt][1] * sc, acc[nt][2] * sc, acc[nt][3] * sc);
    }
    __syncthreads();   // barrier 2: sK/sQ visible; staging dead -> sPx writable

    // ---------- Scores + exp/mask + normalize; P -> regs (+ own slot of sPx) ----------
    bf16x4 pa[4];   // pa[kt]: P[l=kt*16+quad*4+r][t=shalf*16+lm], normalized
    {
        bf16x8 a[4], b;
        #pragma unroll
        for (int mt = 0; mt < 4; ++mt)
            a[mt] = *(const bf16x8*)&sK[swz128(mt * 16 + lm, fbase + quad * 8)];
        b = *(const bf16x8*)&sQ[swz128(shalf * 16 + lm, fbase + quad * 8)];
        const int t = shalf * 16 + lm;
        const bool tok = (t < T_);
        const unsigned long long msh = (tok ? mok : 0ULL) >> (quad * 4);
        const unsigned int mlo = (unsigned int)msh, mhi = (unsigned int)(msh >> 32);
        float e[4][4];
        float psum = 0.f;
        #pragma unroll
        for (int mt = 0; mt < 4; ++mt) {
            f32x4 acc = MFMA(a[mt], b, (f32x4)0.f);   // C[l][t], col t = lm
            const unsigned int mw = (mt >= 2) ? mhi : mlo;
            const int bp = (mt * 16) & 31;
            #pragma unroll
            for (int r = 0; r < 4; ++r) {
                e[mt][r] = ((mw >> (bp + r)) & 1u) ? __expf(acc[r]) : 0.f;
                psum += e[mt][r];
            }
        }
        // full row-sum over l: 4 quads hold disjoint l for the same t
        psum += __shfl_xor(psum, 16, 64);
        psum += __shfl_xor(psum, 32, 64);
        const float inv = (psum > 0.f) ? 1.f / psum : 0.f;   // pad/masked rows -> exact 0
        #pragma unroll
        for (int mt = 0; mt < 4; ++mt) {
            uint2 y = { cvtpk(e[mt][0] * inv, e[mt][1] * inv),
                        cvtpk(e[mt][2] * inv, e[mt][3] * inv) };
            __builtin_memcpy(&pa[mt], &y, 8);
            *(uint2*)&sPx[w * 1024 + swz64(lm, mt * 16 + quad * 4)] = y;
        }
    }
    __syncthreads();   // barrier 2.5: sPx visible; sQ/sK dead -> sO writable

    // ---------- PV: O[t][f-slice] via mfma16, A=V(regs), B=P(regs/partner-LDS) ----------
    {
        bf16x4 pl[4];
        const unsigned short* sPp = sPx + (w ^ 1) * 1024;
        #pragma unroll
        for (int kt = 0; kt < 4; ++kt) {
            uint2 y = *(const uint2*)&sPp[swz64(lm, kt * 16 + quad * 4)];
            __builtin_memcpy(&pl[kt], &y, 8);
        }
        f32x4 o0 = (f32x4)0.f, o1 = (f32x4)0.f;   // t-tiles 0 and 1
        if (shalf == 0) {
            #pragma unroll
            for (int kt = 0; kt < 4; ++kt) {
                o0 = mfma16(vb[kt], pa[kt], o0);
                o1 = mfma16(vb[kt], pl[kt], o1);
            }
        } else {
            #pragma unroll
            for (int kt = 0; kt < 4; ++kt) {
                o0 = mfma16(vb[kt], pl[kt], o0);
                o1 = mfma16(vb[kt], pa[kt], o1);
            }
        }
        // C[f][t]: col t = tau*16+lm, rows f = fs+quad*4+r -> packed sO[t][f] stores
        st4pk(&sO[swz128(lm,      fs + quad * 4)], o0[0], o0[1], o0[2], o0[3]);
        st4pk(&sO[swz128(16 + lm, fs + quad * 4)], o1[0], o1[1], o1[2], o1[3]);
    }

    // ---------- residual preload (fp32-exact; issued before barrier 3) ----------
    float4 res[2];
    #pragma unroll
    for (int nt = 0; nt < 2; ++nt) {
        const int t = nt * 16 + lm;
        res[nt] = make_float4(0.f, 0.f, 0.f, 0.f);
        if (t < T_) {
            const size_t off = ((size_t)t * (B_ * V_) + bv) * F_ + fs + quad * 4;
            if (isBf16) {
                ushort4 u = *(const ushort4*)((const unsigned short*)veh + off);
                res[nt] = make_float4(bf1(u.x), bf1(u.y), bf1(u.z), bf1(u.w));
            } else {
                res[nt] = *(const float4*)((const float*)veh + off);
            }
        }
    }
    __syncthreads();   // barrier 3: sO complete across waves

    // ---------- Phase E (swapped: A=Wc): out = O @ Wc^T + veh ----------
    {
        bf16x8 wc[4];
        #pragma unroll
        for (int kt = 0; kt < 4; ++kt)
            wc[kt] = ldWfrag(Wc, (fs + lm) * 128 + kt * 32 + quad * 8, isBf16);
        f32x4 acc[2];
        acc[0] = (f32x4)0.f; acc[1] = (f32x4)0.f;
        #pragma unroll
        for (int kt = 0; kt < 4; ++kt) {
            bf16x8 b[2];
            #pragma unroll
            for (int nt = 0; nt < 2; ++nt)
                b[nt] = *(const bf16x8*)&sO[swz128(nt * 16 + lm, kt * 32 + quad * 8)];
            #pragma unroll
            for (int nt = 0; nt < 2; ++nt) acc[nt] = MFMA(wc[kt], b[nt], acc[nt]);    // C[g][t]
        }
        #pragma unroll
        for (int nt = 0; nt < 2; ++nt) {
            const int t = nt * 16 + lm;
            if (t < T_) {
                const size_t off = ((size_t)t * (B_ * V_) + bv) * F_ + fs + quad * 4;
                float4 o = make_float4(acc[nt][0] + res[nt].x, acc[nt][1] + res[nt].y,
                                       acc[nt][2] + res[nt].z, acc[nt][3] + res[nt].w);
                *(float4*)&outp[off] = o;
            }
        }
    }
}

extern "C" void kernel_launch(void* const* d_in, const int* in_sizes, int n_in,
                              void* d_out, int out_size, void* d_ws, size_t ws_size,
                              hipStream_t stream) {
    (void)in_sizes; (void)n_in; (void)out_size; (void)d_ws; (void)ws_size;
    lane_attn_kernel<<<dim3(B_ * V_), dim3(512), 0, stream>>>(
        d_in[0], d_in[1], d_in[2], d_in[3], d_in[4], d_in[5], d_in[6],
        (float*)d_out);
}

// Round 5
// 164.697 us; speedup vs baseline: 1.3225x; 1.3225x over previous
//
#include <hip/hip_runtime.h>
#include <hip/hip_bf16.h>

#define T_  30
#define B_  64
#define V_  32
#define F_  128
#define L_  64
#define LF_ 64
#define TH_ 20
#define H_  4
#define HD_ 32

typedef __attribute__((ext_vector_type(8))) short bf16x8;   // 8 bf16 = 4 VGPR
typedef __attribute__((ext_vector_type(4))) short bf16x4;   // 4 bf16 = 2 VGPR
typedef __attribute__((ext_vector_type(4))) float f32x4;
#define MFMA(a,b,c) __builtin_amdgcn_mfma_f32_16x16x32_bf16(a, b, c, 0, 0, 0)

// K=16 bf16 MFMA (v_mfma_f32_16x16x16_bf16), CDNA2 "1k" builtin spelling.
// __HIP_DEVICE_COMPILE__ guard keeps the x86 host pass from parsing it.
__device__ __forceinline__ f32x4 mfma16(bf16x4 a, bf16x4 b, f32x4 c) {
#if defined(__HIP_DEVICE_COMPILE__)
    return __builtin_amdgcn_mfma_f32_16x16x16bf16_1k(a, b, c, 0, 0, 0);
#else
    (void)a; (void)b; return c;
#endif
}

__device__ __forceinline__ float bf1(unsigned short u) {
    unsigned int x = ((unsigned int)u) << 16; float f; __builtin_memcpy(&f, &x, 4); return f;
}
// pack two f32 -> two bf16 (RTNE, v_cvt_pk_bf16_f32); lo half = a, hi half = b
__device__ __forceinline__ unsigned int cvtpk(float a, float b) {
    __hip_bfloat162 h = __float22bfloat162_rn(make_float2(a, b));
    unsigned int r; __builtin_memcpy(&r, &h, 4); return r;
}
__device__ __forceinline__ void st4pk(unsigned short* p, float a, float b, float c, float d) {
    uint2 u = { cvtpk(a, b), cvtpk(c, d) };
    *(uint2*)p = u;
}
// XOR-16B swizzle keyed on row&7 (T2): ushort-index helpers.
__device__ __forceinline__ int swz128(int r, int c) { return r * 128 + (c ^ ((r & 7) << 3)); }
__device__ __forceinline__ int swz64 (int r, int c) { return r * 64  + (c ^ ((r & 7) << 3)); }
// Load one MFMA A/B-fragment (8 bf16) from a weight matrix of either dtype.
__device__ __forceinline__ bf16x8 ldWfrag(const void* W, int off, bool isBf16) {
    if (isBf16) return *(const bf16x8*)((const unsigned short*)W + off);
    const float* p = (const float*)W + off;
    float4 a = *(const float4*)p;
    float4 b = *(const float4*)(p + 4);
    uint4 u = { cvtpk(a.x, a.y), cvtpk(a.z, a.w), cvtpk(b.x, b.y), cvtpk(b.z, b.w) };
    bf16x8 r; __builtin_memcpy(&r, &u, 16); return r;
}

// One block per (b,v). 8 waves: wave w -> head h=w>>1, half s=w&1.
// LDS 40960 B -> 4 blocks/CU x 8 waves = 32 waves/CU (HW cap). Register diet
// vs round 4 (which spilled at the 64-VGPR cap):
//   - weights loaded just-in-time inside their consuming phase (L2-hot),
//   - softmax normalization deferred to the PV epilogue (no e[16] f32 array;
//     unnormalized-exp-in-bf16 validated in earlier rounds),
//   - V exchanged through LDS (sVx) instead of P: pa stays in registers,
//     inv is lane-local at the PV epilogue (C col = own t), no inv exchange.
// Fragment identity (validated round 4): projection C-layouts ARE the K=16
// consumer A/B fragments on the same lane.
__global__ __launch_bounds__(512, 8)
void lane_attn_kernel(const void* __restrict__ veh,    // [T,B,V,F]
                      const void* __restrict__ lanes,  // [B,V,L,LF]
                      const void* __restrict__ maskp,  // [TH,B,V,L] uint8 or int32 (probed)
                      const void* __restrict__ Wk, const void* __restrict__ Wv,
                      const void* __restrict__ Wq, const void* __restrict__ Wc,
                      float* __restrict__ outp)        // [T,B,V,F] fp32
{
    const int bv    = blockIdx.x;
    const int tid   = threadIdx.x;
    const int w     = tid >> 6;
    const int h     = w >> 1;      // head
    const int shalf = w & 1;       // half within head
    const int lane  = tid & 63;
    const int quad  = lane >> 4;
    const int lm    = lane & 15;
    const int fbase = h * 32;
    const int fs    = fbase + shalf * 16;         // wave's own 16-col f-slice
    const int pfs   = fbase + (1 - shalf) * 16;   // partner's f-slice

    // LDS (ushort units), 20480 ushorts = 40960 B total:
    //   sK    [64 l][128 f]   8192 u  (written B-K, read scores)
    //   sReg1 8192 u: sLanes [64][64] + sVehB [32][128]  (A..C)
    //                 -> after bar2: sVx [8 slots][1024]  (V-fragment exchange)
    //   sReg2 4096 u: sQ [32][128] (C..scores) -> after bar2.5: sO [32][128]
    __shared__ __align__(16) unsigned short sK   [8192];
    __shared__ __align__(16) unsigned short sReg1[8192];
    __shared__ __align__(16) unsigned short sReg2[4096];
    unsigned short* sLanes = sReg1;
    unsigned short* sVehB  = sReg1 + 4096;
    unsigned short* sVx    = sReg1;
    unsigned short* sQ     = sReg2;
    unsigned short* sO     = sReg2;

    // ---------- per-wave probes (wave-uniform, no LDS/barrier) ----------
    const unsigned short* vh16 = (const unsigned short*)veh;
    const int field = (vh16[2 * lane] >> 7) & 0xFF;
    const bool isBf16 = __popcll(__ballot(field >= 100 && field <= 130)) >= 32;
    const unsigned char* mbp = (const unsigned char*)maskp;
    const bool maskByte = (__ballot(mbp[4 * lane + 1] != 0) != 0ULL);

    // ---------- per-lane mask OR over TH (l = lane) -> wave-uniform bitmask ----------
    bool ok;
    {
        const int* mi = (const int*)maskp;
        int o = 0;
        #pragma unroll
        for (int th = 0; th < TH_; ++th) {
            const size_t e = (size_t)th * (B_ * V_ * L_) + (size_t)bv * L_ + lane;
            o |= maskByte ? (int)mbp[e] : mi[e];
        }
        ok = (o != 0);
    }
    const unsigned long long mok = __ballot(ok);   // bit l = mask for lane-row l

    // ---------- Phase A: stage lanes[64][64] + veh[32][128] as bf16 (swizzled) ----------
    if (isBf16) {
        {   // lanes: 512 x 16B chunks, one per thread
            const int l = tid >> 3, g = tid & 7;
            uint4 x = *(const uint4*)((const unsigned short*)lanes + (size_t)bv * 4096 + tid * 8);
            *(uint4*)&sLanes[swz64(l, g * 8)] = x;
        }
        {   // veh: 32 rows x 16 granules = 512
            const int t = tid >> 4, g = tid & 15;
            uint4 x = {0, 0, 0, 0};
            if (t < T_)
                x = *(const uint4*)((const unsigned short*)veh + ((size_t)t * (B_ * V_) + bv) * F_ + g * 8);
            *(uint4*)&sVehB[swz128(t, g * 8)] = x;
        }
    } else {
        const float4* lf4 = (const float4*)lanes;
        #pragma unroll
        for (int rr = 0; rr < 2; ++rr) {
            const int u = tid + rr * 512;
            const int l = u >> 4, c = (u & 15) * 4;
            float4 x = lf4[bv * 1024 + u];
            uint2 y = { cvtpk(x.x, x.y), cvtpk(x.z, x.w) };
            *(uint2*)&sLanes[swz64(l, c)] = y;
        }
        #pragma unroll
        for (int rr = 0; rr < 2; ++rr) {
            const int u = tid + rr * 512;
            const int t = u >> 5, c = (u & 31) * 4;
            uint2 y = {0, 0};
            if (t < T_) {
                float4 x = ((const float4*)veh)[((size_t)t * (B_ * V_) + bv) * 32 + (u & 31)];
                y.x = cvtpk(x.x, x.y); y.y = cvtpk(x.z, x.w);
            }
            *(uint2*)&sVehB[swz128(t, c)] = y;
        }
    }
    __syncthreads();   // barrier 1: staging visible

    // ---------- Phase B-K: K projection (swapped: A=Wk, JIT) -> sK[l][f] packed ----------
    {
        bf16x8 wbK[2];
        #pragma unroll
        for (int kt = 0; kt < 2; ++kt)
            wbK[kt] = ldWfrag(Wk, (fs + lm) * 64 + kt * 32 + quad * 8, isBf16);
        f32x4 accK[4];
        #pragma unroll
        for (int mt = 0; mt < 4; ++mt) accK[mt] = (f32x4)0.f;
        #pragma unroll
        for (int kt = 0; kt < 2; ++kt) {
            bf16x8 a[4];
            #pragma unroll
            for (int mt = 0; mt < 4; ++mt)
                a[mt] = *(const bf16x8*)&sLanes[swz64(mt * 16 + lm, kt * 32 + quad * 8)];
            #pragma unroll
            for (int mt = 0; mt < 4; ++mt) accK[mt] = MFMA(wbK[kt], a[mt], accK[mt]);  // C[f][l]
        }
        #pragma unroll
        for (int mt = 0; mt < 4; ++mt)
            st4pk(&sK[swz128(mt * 16 + lm, fs + quad * 4)],
                  accK[mt][0], accK[mt][1], accK[mt][2], accK[mt][3]);
    }

    // ---------- Phase B-V: V projection (unswapped, JIT) -> registers as PV A-frags ----------
    bf16x4 vb[4];   // vb[kt]: V[l=kt*16+quad*4+r][f=fs+lm]
    {
        bf16x8 wbV[2];
        #pragma unroll
        for (int kt = 0; kt < 2; ++kt)
            wbV[kt] = ldWfrag(Wv, (fs + lm) * 64 + kt * 32 + quad * 8, isBf16);
        f32x4 accV[4];
        #pragma unroll
        for (int mt = 0; mt < 4; ++mt) accV[mt] = (f32x4)0.f;
        #pragma unroll
        for (int kt = 0; kt < 2; ++kt) {
            bf16x8 a[4];
            #pragma unroll
            for (int mt = 0; mt < 4; ++mt)
                a[mt] = *(const bf16x8*)&sLanes[swz64(mt * 16 + lm, kt * 32 + quad * 8)];
            #pragma unroll
            for (int mt = 0; mt < 4; ++mt) accV[mt] = MFMA(a[mt], wbV[kt], accV[mt]);  // C[l][f]
        }
        #pragma unroll
        for (int mt = 0; mt < 4; ++mt) {
            uint2 y = { cvtpk(accV[mt][0], accV[mt][1]), cvtpk(accV[mt][2], accV[mt][3]) };
            __builtin_memcpy(&vb[mt], &y, 8);
        }
    }

    // ---------- Phase C: Q projection (swapped: A=Wq, JIT) -> sQ[t][g] packed, pre-scaled ----------
    {
        bf16x8 wq[4];
        #pragma unroll
        for (int kt = 0; kt < 4; ++kt)
            wq[kt] = ldWfrag(Wq, (fs + lm) * 128 + kt * 32 + quad * 8, isBf16);
        f32x4 acc[2];
        acc[0] = (f32x4)0.f; acc[1] = (f32x4)0.f;
        #pragma unroll
        for (int kt = 0; kt < 4; ++kt) {
            bf16x8 b[2];
            #pragma unroll
            for (int nt = 0; nt < 2; ++nt)
                b[nt] = *(const bf16x8*)&sVehB[swz128(nt * 16 + lm, kt * 32 + quad * 8)];
            #pragma unroll
            for (int nt = 0; nt < 2; ++nt) acc[nt] = MFMA(wq[kt], b[nt], acc[nt]);     // C[g][t]
        }
        const float sc = 0.17677669529663687f;   // 1/sqrt(32)
        #pragma unroll
        for (int nt = 0; nt < 2; ++nt)
            st4pk(&sQ[swz128(nt * 16 + lm, fs + quad * 4)],
                  acc[nt][0] * sc, acc[nt][1] * sc, acc[nt][2] * sc, acc[nt][3] * sc);
    }
    __syncthreads();   // barrier 2: sK/sQ visible; staging dead -> sVx writable

    // ---------- V-fragment exchange: wave slot w, plain layout, 2-way bank alias ----------
    #pragma unroll
    for (int kt = 0; kt < 4; ++kt) {
        uint2 y; __builtin_memcpy(&y, &vb[kt], 8);
        *(uint2*)&sVx[w * 1024 + kt * 256 + lane * 4] = y;
    }

    // ---------- Scores + exp/mask; UNNORMALIZED P -> registers only; inv kept ----------
    bf16x4 pa[4];   // pa[kt]: exp(S)[l=kt*16+quad*4+r][t=shalf*16+lm]
    float inv;
    {
        bf16x8 a[4], b;
        #pragma unroll
        for (int mt = 0; mt < 4; ++mt)
            a[mt] = *(const bf16x8*)&sK[swz128(mt * 16 + lm, fbase + quad * 8)];
        b = *(const bf16x8*)&sQ[swz128(shalf * 16 + lm, fbase + quad * 8)];
        const int t = shalf * 16 + lm;
        const bool tok = (t < T_);
        const unsigned long long msh = (tok ? mok : 0ULL) >> (quad * 4);
        const unsigned int mlo = (unsigned int)msh, mhi = (unsigned int)(msh >> 32);
        float psum = 0.f;
        #pragma unroll
        for (int mt = 0; mt < 4; ++mt) {
            f32x4 acc = MFMA(a[mt], b, (f32x4)0.f);   // C[l][t], col t = lm
            const unsigned int mw = (mt >= 2) ? mhi : mlo;
            const int bp = (mt * 16) & 31;
            float e0 = ((mw >> (bp + 0)) & 1u) ? __expf(acc[0]) : 0.f;
            float e1 = ((mw >> (bp + 1)) & 1u) ? __expf(acc[1]) : 0.f;
            float e2 = ((mw >> (bp + 2)) & 1u) ? __expf(acc[2]) : 0.f;
            float e3 = ((mw >> (bp + 3)) & 1u) ? __expf(acc[3]) : 0.f;
            psum += (e0 + e1) + (e2 + e3);
            uint2 y = { cvtpk(e0, e1), cvtpk(e2, e3) };
            __builtin_memcpy(&pa[mt], &y, 8);
        }
        // full row-sum over l: 4 quads hold disjoint l for the same t
        psum += __shfl_xor(psum, 16, 64);
        psum += __shfl_xor(psum, 32, 64);
        inv = (psum > 0.f) ? 1.f / psum : 0.f;   // pad/masked rows -> exact 0
    }
    __syncthreads();   // barrier 2.5: sVx visible; sK/sQ dead -> sO writable

    // ---------- PV: O[f own+partner][t own] via mfma16; normalize by lane-local inv ----------
    {
        f32x4 o0 = (f32x4)0.f, o1 = (f32x4)0.f;   // own-f tile, partner-f tile
        #pragma unroll
        for (int kt = 0; kt < 4; ++kt) {
            uint2 y = *(const uint2*)&sVx[(w ^ 1) * 1024 + kt * 256 + lane * 4];
            bf16x4 vx; __builtin_memcpy(&vx, &y, 8);
            o0 = mfma16(vb[kt], pa[kt], o0);
            o1 = mfma16(vx,     pa[kt], o1);
        }
        // C[f][t]: col t = shalf*16+lm (lane-local inv), rows f = f0+quad*4+r
        const int t = shalf * 16 + lm;
        st4pk(&sO[swz128(t, fs  + quad * 4)],
              o0[0] * inv, o0[1] * inv, o0[2] * inv, o0[3] * inv);
        st4pk(&sO[swz128(t, pfs + quad * 4)],
              o1[0] * inv, o1[1] * inv, o1[2] * inv, o1[3] * inv);
    }

    // ---------- residual preload (fp32-exact; issued before barrier 3) ----------
    float4 res[2];
    #pragma unroll
    for (int nt = 0; nt < 2; ++nt) {
        const int t = nt * 16 + lm;
        res[nt] = make_float4(0.f, 0.f, 0.f, 0.f);
        if (t < T_) {
            const size_t off = ((size_t)t * (B_ * V_) + bv) * F_ + fs + quad * 4;
            if (isBf16) {
                ushort4 u = *(const ushort4*)((const unsigned short*)veh + off);
                res[nt] = make_float4(bf1(u.x), bf1(u.y), bf1(u.z), bf1(u.w));
            } else {
                res[nt] = *(const float4*)((const float*)veh + off);
            }
        }
    }
    __syncthreads();   // barrier 3: sO complete across waves

    // ---------- Phase E (swapped: A=Wc, JIT): out = O @ Wc^T + veh ----------
    {
        bf16x8 wc[4];
        #pragma unroll
        for (int kt = 0; kt < 4; ++kt)
            wc[kt] = ldWfrag(Wc, (fs + lm) * 128 + kt * 32 + quad * 8, isBf16);
        f32x4 acc[2];
        acc[0] = (f32x4)0.f; acc[1] = (f32x4)0.f;
        #pragma unroll
        for (int kt = 0; kt < 4; ++kt) {
            bf16x8 b[2];
            #pragma unroll
            for (int nt = 0; nt < 2; ++nt)
                b[nt] = *(const bf16x8*)&sO[swz128(nt * 16 + lm, kt * 32 + quad * 8)];
            #pragma unroll
            for (int nt = 0; nt < 2; ++nt) acc[nt] = MFMA(wc[kt], b[nt], acc[nt]);    // C[g][t]
        }
        #pragma unroll
        for (int nt = 0; nt < 2; ++nt) {
            const int t = nt * 16 + lm;
            if (t < T_) {
                const size_t off = ((size_t)t * (B_ * V_) + bv) * F_ + fs + quad * 4;
                float4 o = make_float4(acc[nt][0] + res[nt].x, acc[nt][1] + res[nt].y,
                                       acc[nt][2] + res[nt].z, acc[nt][3] + res[nt].w);
                *(float4*)&outp[off] = o;
            }
        }
    }
}

extern "C" void kernel_launch(void* const* d_in, const int* in_sizes, int n_in,
                              void* d_out, int out_size, void* d_ws, size_t ws_size,
                              hipStream_t stream) {
    (void)in_sizes; (void)n_in; (void)out_size; (void)d_ws; (void)ws_size;
    lane_attn_kernel<<<dim3(B_ * V_), dim3(512), 0, stream>>>(
        d_in[0], d_in[1], d_in[2], d_in[3], d_in[4], d_in[5], d_in[6],
        (float*)d_out);
}